// Round 3
// baseline (38.212 us; speedup 1.0000x reference)
//
#include <hip/hip_runtime.h>
#include <math.h>

#define NCLUST 16
#define MAIN_BLOCKS 1024
#define MAIN_THREADS 256

// Fused single-dispatch kernel: stream X -> per-block double partials ->
// last-block finalize (device-scope atomic ticket) -> scalar out.
// Deterministic: partials are per-block, finalize reduction order fixed.
__global__ __launch_bounds__(MAIN_THREADS) void gmm_fused_kernel(
    const float* __restrict__ X,
    const float* __restrict__ means,
    const float* __restrict__ chols,
    const float* __restrict__ weights,
    unsigned int* __restrict__ ticket,   // zeroed each call via hipMemsetAsync
    double* __restrict__ partials,
    float* __restrict__ out,
    int nvec, int nsamples)
{
    __shared__ float par[NCLUST][8];   // A,B,C,D,E,F,sign
    __shared__ float sS[NCLUST][6];    // s11,s12,s22,mx,my,w  (for z in finalize)
    const int tid = threadIdx.x;
    if (tid < NCLUST) {
        const int k = tid;
        // chols layout [K,2,2] row-major; tril -> L00, L10, L11
        const float c00 = chols[4*k + 0];
        const float c10 = chols[4*k + 2];
        const float c11 = chols[4*k + 3];
        // S = L L^T
        const float s11 = c00*c00;
        const float s12 = c00*c10;
        const float s22 = c10*c10 + c11*c11;
        const float det = s11*s22 - s12*s12;
        const float invdet = 1.0f / det;
        const float KC = -0.7213475204444817f;   // -0.5 * log2(e)
        const float A = KC * s22 * invdet;
        const float B = KC * (-2.0f * s12) * invdet;
        const float C = KC * s11 * invdet;
        const float mx = means[2*k + 0];
        const float my = means[2*k + 1];
        const float w  = weights[k];
        const float coef = w / (6.283185307179586f * sqrtf(det));
        // expand around mean: t(x,y) = A x^2 + B xy + C y^2 + D x + E y + F
        const float D = -(2.0f*A*mx + B*my);
        const float E = -(2.0f*C*my + B*mx);
        const float F = A*mx*mx + B*mx*my + C*my*my + log2f(fabsf(coef));
        par[k][0] = A;  par[k][1] = B;  par[k][2] = C;
        par[k][3] = D;  par[k][4] = E;  par[k][5] = F;
        par[k][6] = (coef < 0.0f) ? -1.0f : 1.0f;
        sS[k][0] = s11; sS[k][1] = s12; sS[k][2] = s22;
        sS[k][3] = mx;  sS[k][4] = my;  sS[k][5] = w;
    }
    __syncthreads();

    // hoist params into registers (statically indexed after unroll)
    float a[NCLUST], b[NCLUST], c[NCLUST], d[NCLUST], e[NCLUST], f[NCLUST], sg[NCLUST];
    #pragma unroll
    for (int k = 0; k < NCLUST; ++k) {
        a[k] = par[k][0]; b[k] = par[k][1]; c[k] = par[k][2];
        d[k] = par[k][3]; e[k] = par[k][4]; f[k] = par[k][5];
        sg[k] = par[k][6];
    }

    const float4* __restrict__ X4 = (const float4*)X;
    float acc = 0.0f;
    const int stride = MAIN_BLOCKS * MAIN_THREADS;
    for (int i = blockIdx.x * MAIN_THREADS + tid; i < nvec; i += stride) {
        const float4 v = X4[i];   // two samples: (v.x,v.y), (v.z,v.w)
        const float xx0 = v.x*v.x, xy0 = v.x*v.y, yy0 = v.y*v.y;
        const float xx1 = v.z*v.z, xy1 = v.z*v.w, yy1 = v.w*v.w;
        float g0 = 0.0f, g1 = 0.0f;
        #pragma unroll
        for (int k = 0; k < NCLUST; ++k) {
            float t0 = fmaf(a[k], xx0,
                       fmaf(b[k], xy0,
                       fmaf(c[k], yy0,
                       fmaf(d[k], v.x,
                       fmaf(e[k], v.y, f[k])))));
            g0 = fmaf(sg[k], exp2f(t0), g0);
            float t1 = fmaf(a[k], xx1,
                       fmaf(b[k], xy1,
                       fmaf(c[k], yy1,
                       fmaf(d[k], v.z,
                       fmaf(e[k], v.w, f[k])))));
            g1 = fmaf(sg[k], exp2f(t1), g1);
        }
        acc = fmaf(g0, g0, acc);
        acc = fmaf(g1, g1, acc);
    }

    // wave (64-lane) reduction, then cross-wave via LDS
    #pragma unroll
    for (int off = 32; off > 0; off >>= 1)
        acc += __shfl_down(acc, off, 64);
    __shared__ float wsum[MAIN_THREADS / 64];
    if ((tid & 63) == 0) wsum[tid >> 6] = acc;
    __syncthreads();

    __shared__ int is_last;
    if (tid == 0) {
        float s = 0.0f;
        #pragma unroll
        for (int w = 0; w < MAIN_THREADS / 64; ++w) s += wsum[w];
        partials[blockIdx.x] = (double)s;
        __threadfence();                                   // release partials
        unsigned int t = atomicAdd(ticket, 1u);            // device-scope
        is_last = (t == (unsigned int)(MAIN_BLOCKS - 1)) ? 1 : 0;
    }
    __syncthreads();
    if (!is_last) return;
    __threadfence();                                       // acquire partials

    // ---- finalize (last block only) ----
    // one (i,j) cluster pair per thread (256 = 16*16)
    const int i = tid >> 4, j = tid & 15;
    const float t11 = sS[i][0] + sS[j][0];
    const float t12 = sS[i][1] + sS[j][1];
    const float t22 = sS[i][2] + sS[j][2];
    const float det = t11*t22 - t12*t12;
    const float mdx = sS[i][3] - sS[j][3];
    const float mdy = sS[i][4] - sS[j][4];
    const float m2 = (t22*mdx*mdx - 2.0f*t12*mdx*mdy + t11*mdy*mdy) / det;
    const float Zij = expf(-0.5f * m2) / (6.283185307179586f * sqrtf(det));
    double zc = (double)(sS[i][5] * sS[j][5] * Zij);

    // sum the per-block g^2 partials (fixed order)
    double ps = 0.0;
    for (int bi = tid; bi < MAIN_BLOCKS; bi += MAIN_THREADS) ps += partials[bi];

    // odd-sample tail (not hit for N=2M, kept for generality)
    if (tid == 0 && (nsamples & 1)) {
        const float x = X[2*(nsamples-1)], y = X[2*(nsamples-1)+1];
        float g = 0.0f;
        #pragma unroll
        for (int k = 0; k < NCLUST; ++k) {
            float t = fmaf(par[k][0], x*x,
                      fmaf(par[k][1], x*y,
                      fmaf(par[k][2], y*y,
                      fmaf(par[k][3], x,
                      fmaf(par[k][4], y, par[k][5])))));
            g = fmaf(par[k][6], exp2f(t), g);
        }
        ps += (double)(g*g);
    }

    __shared__ double red[MAIN_THREADS], red2[MAIN_THREADS];
    red[tid] = ps;
    red2[tid] = zc;
    __syncthreads();
    for (int s = 128; s > 0; s >>= 1) {
        if (tid < s) { red[tid] += red[tid + s]; red2[tid] += red2[tid + s]; }
        __syncthreads();
    }
    if (tid == 0) {
        const double total = red[0];   // sum_n g(x_n)^2
        const double z = red2[0];      // pair normalizer
        out[0] = (float)(-(log(total) - log(z)) / (double)nsamples);
    }
}

extern "C" void kernel_launch(void* const* d_in, const int* in_sizes, int n_in,
                              void* d_out, int out_size, void* d_ws, size_t ws_size,
                              hipStream_t stream)
{
    const float* X       = (const float*)d_in[0];
    const float* means   = (const float*)d_in[1];
    const float* chols   = (const float*)d_in[2];
    const float* weights = (const float*)d_in[3];
    float* out = (float*)d_out;

    // d_ws layout: [0,4) ticket counter; [256, 256 + 8*MAIN_BLOCKS) partials
    unsigned int* ticket = (unsigned int*)d_ws;
    double* partials = (double*)((char*)d_ws + 256);

    const int nsamples = in_sizes[0] / 2;   // X is [N,2]
    const int nvec = nsamples / 2;          // float4 = 2 samples

    hipMemsetAsync(ticket, 0, sizeof(unsigned int), stream);
    gmm_fused_kernel<<<MAIN_BLOCKS, MAIN_THREADS, 0, stream>>>(
        X, means, chols, weights, ticket, partials, out, nvec, nsamples);
}